// Round 1
// baseline (737.736 us; speedup 1.0000x reference)
//
#include <hip/hip_runtime.h>
#include <hip/hip_bf16.h>

#define NB 64
#define NP 2048
#define ND 1024

typedef __bf16 bf16x8 __attribute__((ext_vector_type(8)));
typedef __bf16 bf16x4 __attribute__((ext_vector_type(4)));
typedef float  f32x4  __attribute__((ext_vector_type(4)));

// ---------------------------------------------------------------------------
// Kernel 0: convert disFtr (64x1024 fp32) -> bf16 copy in workspace.
// ---------------------------------------------------------------------------
__global__ void cvt_dis_kernel(const float* __restrict__ src,
                               __bf16* __restrict__ dst) {
    int i = (blockIdx.x * blockDim.x + threadIdx.x) * 4;
    float4 v = *(const float4*)(src + i);
    bf16x4 o;
    o[0] = (__bf16)v.x; o[1] = (__bf16)v.y;
    o[2] = (__bf16)v.z; o[3] = (__bf16)v.w;
    *(bf16x4*)(dst + i) = o;
}

// ---------------------------------------------------------------------------
// Kernel 1: fused GEMM + max-over-p.
// Grid: 1024 blocks = 64 batches x 16 p-tiles(128 rows). Block: 256 thr.
// Wave w handles rows [ptile*128 + w*32, +32), all 64 cols, via
// 2(row-tiles) x 4(col-tiles) mfma_f32_16x16x32_bf16 fragments.
// A loaded direct from global fp32 (16 rows x 128B lines per instr),
// converted to bf16 in-register. B loaded from bf16 ws copy (L2-hot).
// Epilogue reduces max over the 128 rows -> partial[b*16+pt][64].
// ---------------------------------------------------------------------------
__global__ __launch_bounds__(256, 4)
void simmax_kernel(const float* __restrict__ im,
                   const __bf16* __restrict__ dis,
                   float* __restrict__ partial) {
    int b    = blockIdx.x >> 4;
    int pt   = blockIdx.x & 15;
    int w    = threadIdx.x >> 6;
    int lane = threadIdx.x & 63;
    int quad = lane >> 4;
    int lrow = lane & 15;

    long p0 = (long)pt * 128 + w * 32;
    const float*  a0 = im + ((long)b * NP + p0 + lrow) * ND + quad * 8;
    const float*  a1 = a0 + 16 * ND;
    const __bf16* bp = dis + lrow * ND + quad * 8;

    f32x4 zero = {0.f, 0.f, 0.f, 0.f};
    f32x4 acc[2][4];
#pragma unroll
    for (int r = 0; r < 2; ++r)
#pragma unroll
        for (int t = 0; t < 4; ++t) acc[r][t] = zero;

    for (int k = 0; k < ND; k += 32) {
        bf16x8 av0, av1;
        {
            float4 x0 = *(const float4*)(a0 + k);
            float4 x1 = *(const float4*)(a0 + k + 4);
            av0[0] = (__bf16)x0.x; av0[1] = (__bf16)x0.y;
            av0[2] = (__bf16)x0.z; av0[3] = (__bf16)x0.w;
            av0[4] = (__bf16)x1.x; av0[5] = (__bf16)x1.y;
            av0[6] = (__bf16)x1.z; av0[7] = (__bf16)x1.w;
            float4 y0 = *(const float4*)(a1 + k);
            float4 y1 = *(const float4*)(a1 + k + 4);
            av1[0] = (__bf16)y0.x; av1[1] = (__bf16)y0.y;
            av1[2] = (__bf16)y0.z; av1[3] = (__bf16)y0.w;
            av1[4] = (__bf16)y1.x; av1[5] = (__bf16)y1.y;
            av1[6] = (__bf16)y1.z; av1[7] = (__bf16)y1.w;
        }
        bf16x8 bv[4];
#pragma unroll
        for (int t = 0; t < 4; ++t)
            bv[t] = *(const bf16x8*)(bp + t * 16 * ND + k);
#pragma unroll
        for (int t = 0; t < 4; ++t) {
            acc[0][t] = __builtin_amdgcn_mfma_f32_16x16x32_bf16(av0, bv[t], acc[0][t], 0, 0, 0);
            acc[1][t] = __builtin_amdgcn_mfma_f32_16x16x32_bf16(av1, bv[t], acc[1][t], 0, 0, 0);
        }
    }

    // Per-lane max over this lane's 8 rows (2 row-tiles x 4 regs), per col-tile.
    // C/D layout: col = lane&15, row = quad*4+reg (row identity irrelevant:
    // we max over all rows). Cross-quad max via xor-shuffles 16, 32.
    float m[4];
#pragma unroll
    for (int t = 0; t < 4; ++t) {
        float v = acc[0][t][0];
#pragma unroll
        for (int i = 1; i < 4; ++i) v = fmaxf(v, acc[0][t][i]);
#pragma unroll
        for (int i = 0; i < 4; ++i) v = fmaxf(v, acc[1][t][i]);
        v = fmaxf(v, __shfl_xor(v, 16));
        v = fmaxf(v, __shfl_xor(v, 32));
        m[t] = v;
    }

    __shared__ float red[4][64];
    if (lane < 16) {
#pragma unroll
        for (int t = 0; t < 4; ++t) red[w][t * 16 + lane] = m[t];
    }
    __syncthreads();
    if (threadIdx.x < 64) {
        float v = fmaxf(fmaxf(red[0][threadIdx.x], red[1][threadIdx.x]),
                        fmaxf(red[2][threadIdx.x], red[3][threadIdx.x]));
        partial[((long)b * 16 + pt) * 64 + threadIdx.x] = v;
    }
}

// ---------------------------------------------------------------------------
// Kernel 2: reduce partials -> simMax[64][64] in LDS, compute hinge loss.
// loss = sum_{i,j: lbl[i]!=lbl[j]} [relu(sim[i][j]-sim[i][i]+0.1)
//                                 + relu(sim[j][i]-sim[i][i]+0.1)] / (cnt+1e-6)
// ---------------------------------------------------------------------------
__global__ void loss_kernel(const float* __restrict__ partial,
                            const int* __restrict__ lbl,
                            float* __restrict__ out) {
    __shared__ float ssim[64][64];
    __shared__ int   slbl[64];
    __shared__ float rsum[16], rcnt[16];
    int tid = threadIdx.x;  // 1024 threads

    for (int e = tid; e < 4096; e += 1024) {
        int i = e >> 6, j = e & 63;
        float mx = -3.4e38f;
        const float* p = partial + (long)i * 16 * 64 + j;
#pragma unroll
        for (int q = 0; q < 16; ++q) mx = fmaxf(mx, p[q * 64]);
        ssim[i][j] = mx;
    }
    if (tid < 64) slbl[tid] = lbl[tid];
    __syncthreads();

    float lsum = 0.f, cnt = 0.f;
    for (int e = tid; e < 4096; e += 1024) {
        int i = e >> 6, j = e & 63;
        if (slbl[i] != slbl[j]) {
            cnt += 1.f;
            float posi = ssim[i][i];
            lsum += fmaxf(ssim[i][j] - posi + 0.1f, 0.f)
                  + fmaxf(ssim[j][i] - posi + 0.1f, 0.f);
        }
    }
#pragma unroll
    for (int o = 32; o > 0; o >>= 1) {
        lsum += __shfl_down(lsum, o);
        cnt  += __shfl_down(cnt, o);
    }
    int wv = tid >> 6;
    if ((tid & 63) == 0) { rsum[wv] = lsum; rcnt[wv] = cnt; }
    __syncthreads();
    if (tid == 0) {
        float S = 0.f, C = 0.f;
        for (int q = 0; q < 16; ++q) { S += rsum[q]; C += rcnt[q]; }
        out[0] = S / (C + 1e-6f);
    }
}

// ---------------------------------------------------------------------------
extern "C" void kernel_launch(void* const* d_in, const int* in_sizes, int n_in,
                              void* d_out, int out_size, void* d_ws, size_t ws_size,
                              hipStream_t stream) {
    const float* imFtr  = (const float*)d_in[0];  // 64 x 2048 x 1024 fp32
    const float* disFtr = (const float*)d_in[1];  // 64 x 1024 fp32
    const int*   lbl    = (const int*)d_in[2];    // 64 int
    float* out = (float*)d_out;

    __bf16* dis_bf   = (__bf16*)d_ws;                          // 128 KB
    float*  partial  = (float*)((char*)d_ws + NB * ND * 2);    // 256 KB

    cvt_dis_kernel<<<64, 256, 0, stream>>>(disFtr, dis_bf);
    simmax_kernel<<<1024, 256, 0, stream>>>(imFtr, dis_bf, partial);
    loss_kernel<<<1, 1024, 0, stream>>>(partial, lbl, out);
}

// Round 3
// 727.839 us; speedup vs baseline: 1.0136x; 1.0136x over previous
//
#include <hip/hip_runtime.h>
#include <hip/hip_bf16.h>

#define NB 64
#define NP 2048
#define ND 1024

typedef __bf16 bf16x8 __attribute__((ext_vector_type(8)));
typedef __bf16 bf16x4 __attribute__((ext_vector_type(4)));
typedef float  f32x4  __attribute__((ext_vector_type(4)));

// ---------------------------------------------------------------------------
// Kernel 0: convert disFtr (64x1024 fp32) -> bf16 copy in workspace.
// ---------------------------------------------------------------------------
__global__ void cvt_dis_kernel(const float* __restrict__ src,
                               __bf16* __restrict__ dst) {
    int i = (blockIdx.x * blockDim.x + threadIdx.x) * 4;
    f32x4 v = *(const f32x4*)(src + i);
    bf16x4 o;
    o[0] = (__bf16)v[0]; o[1] = (__bf16)v[1];
    o[2] = (__bf16)v[2]; o[3] = (__bf16)v[3];
    *(bf16x4*)(dst + i) = o;
}

// ---------------------------------------------------------------------------
// Kernel 1: fused GEMM + max-over-p.
// Grid: 1024 blocks = 64 batches x 16 p-tiles(128 rows). Block: 256 thr.
// Wave w: rows [pt*128 + w*32, +32), all 64 cols, 2x4 mfma_f32_16x16x32_bf16.
// A: direct non-temporal global fp32 loads (no reuse -> don't pollute L2),
//    software-pipelined depth 1 so next k-step's loads are in flight during
//    the current cvt+MFMA. B: bf16 ws copy, L2-resident.
// ---------------------------------------------------------------------------
#define CVT8(dst, p0, p1)                                                  \
    dst[0] = (__bf16)p0[0]; dst[1] = (__bf16)p0[1];                        \
    dst[2] = (__bf16)p0[2]; dst[3] = (__bf16)p0[3];                        \
    dst[4] = (__bf16)p1[0]; dst[5] = (__bf16)p1[1];                        \
    dst[6] = (__bf16)p1[2]; dst[7] = (__bf16)p1[3];

__global__ __launch_bounds__(256, 4)
void simmax_kernel(const float* __restrict__ im,
                   const __bf16* __restrict__ dis,
                   float* __restrict__ partial) {
    int b    = blockIdx.x >> 4;
    int pt   = blockIdx.x & 15;
    int w    = threadIdx.x >> 6;
    int lane = threadIdx.x & 63;
    int quad = lane >> 4;
    int lrow = lane & 15;

    long p0 = (long)pt * 128 + w * 32;
    const float*  a0 = im + ((long)b * NP + p0 + lrow) * ND + quad * 8;
    const float*  a1 = a0 + 16 * ND;
    const __bf16* bp = dis + lrow * ND + quad * 8;

    f32x4 zero = {0.f, 0.f, 0.f, 0.f};
    f32x4 acc[2][4];
#pragma unroll
    for (int r = 0; r < 2; ++r)
#pragma unroll
        for (int t = 0; t < 4; ++t) acc[r][t] = zero;

    // prologue: k=0 A loads in flight
    f32x4 x0 = __builtin_nontemporal_load((const f32x4*)(a0));
    f32x4 x1 = __builtin_nontemporal_load((const f32x4*)(a0 + 4));
    f32x4 y0 = __builtin_nontemporal_load((const f32x4*)(a1));
    f32x4 y1 = __builtin_nontemporal_load((const f32x4*)(a1 + 4));

    for (int k = 0; k < ND - 32; k += 32) {
        // prefetch k+32 A before consuming current
        f32x4 px0 = __builtin_nontemporal_load((const f32x4*)(a0 + k + 32));
        f32x4 px1 = __builtin_nontemporal_load((const f32x4*)(a0 + k + 36));
        f32x4 py0 = __builtin_nontemporal_load((const f32x4*)(a1 + k + 32));
        f32x4 py1 = __builtin_nontemporal_load((const f32x4*)(a1 + k + 36));

        bf16x8 bv[4];
#pragma unroll
        for (int t = 0; t < 4; ++t)
            bv[t] = *(const bf16x8*)(bp + t * 16 * ND + k);

        bf16x8 av0, av1;
        CVT8(av0, x0, x1)
        CVT8(av1, y0, y1)
#pragma unroll
        for (int t = 0; t < 4; ++t) {
            acc[0][t] = __builtin_amdgcn_mfma_f32_16x16x32_bf16(av0, bv[t], acc[0][t], 0, 0, 0);
            acc[1][t] = __builtin_amdgcn_mfma_f32_16x16x32_bf16(av1, bv[t], acc[1][t], 0, 0, 0);
        }
        x0 = px0; x1 = px1; y0 = py0; y1 = py1;
    }
    {   // epilogue iteration k = ND-32
        const int k = ND - 32;
        bf16x8 bv[4];
#pragma unroll
        for (int t = 0; t < 4; ++t)
            bv[t] = *(const bf16x8*)(bp + t * 16 * ND + k);
        bf16x8 av0, av1;
        CVT8(av0, x0, x1)
        CVT8(av1, y0, y1)
#pragma unroll
        for (int t = 0; t < 4; ++t) {
            acc[0][t] = __builtin_amdgcn_mfma_f32_16x16x32_bf16(av0, bv[t], acc[0][t], 0, 0, 0);
            acc[1][t] = __builtin_amdgcn_mfma_f32_16x16x32_bf16(av1, bv[t], acc[1][t], 0, 0, 0);
        }
    }

    // Per-lane max over this lane's 8 rows (2 row-tiles x 4 regs), per col-tile.
    // C/D layout: col = lane&15, row = quad*4+reg (row identity irrelevant:
    // we max over all rows). Cross-quad max via xor-shuffles 16, 32.
    float m[4];
#pragma unroll
    for (int t = 0; t < 4; ++t) {
        float v = acc[0][t][0];
#pragma unroll
        for (int i = 1; i < 4; ++i) v = fmaxf(v, acc[0][t][i]);
#pragma unroll
        for (int i = 0; i < 4; ++i) v = fmaxf(v, acc[1][t][i]);
        v = fmaxf(v, __shfl_xor(v, 16));
        v = fmaxf(v, __shfl_xor(v, 32));
        m[t] = v;
    }

    __shared__ float red[4][64];
    if (lane < 16) {
#pragma unroll
        for (int t = 0; t < 4; ++t) red[w][t * 16 + lane] = m[t];
    }
    __syncthreads();
    if (threadIdx.x < 64) {
        float v = fmaxf(fmaxf(red[0][threadIdx.x], red[1][threadIdx.x]),
                        fmaxf(red[2][threadIdx.x], red[3][threadIdx.x]));
        partial[((long)b * 16 + pt) * 64 + threadIdx.x] = v;
    }
}

// ---------------------------------------------------------------------------
// Kernel 2: reduce partials -> simMax[64][64] in LDS, compute hinge loss.
// loss = sum_{i,j: lbl[i]!=lbl[j]} [relu(sim[i][j]-sim[i][i]+0.1)
//                                 + relu(sim[j][i]-sim[i][i]+0.1)] / (cnt+1e-6)
// ---------------------------------------------------------------------------
__global__ void loss_kernel(const float* __restrict__ partial,
                            const int* __restrict__ lbl,
                            float* __restrict__ out) {
    __shared__ float ssim[64][64];
    __shared__ int   slbl[64];
    __shared__ float rsum[16], rcnt[16];
    int tid = threadIdx.x;  // 1024 threads

    for (int e = tid; e < 4096; e += 1024) {
        int i = e >> 6, j = e & 63;
        float mx = -3.4e38f;
        const float* p = partial + (long)i * 16 * 64 + j;
#pragma unroll
        for (int q = 0; q < 16; ++q) mx = fmaxf(mx, p[q * 64]);
        ssim[i][j] = mx;
    }
    if (tid < 64) slbl[tid] = lbl[tid];
    __syncthreads();

    float lsum = 0.f, cnt = 0.f;
    for (int e = tid; e < 4096; e += 1024) {
        int i = e >> 6, j = e & 63;
        if (slbl[i] != slbl[j]) {
            cnt += 1.f;
            float posi = ssim[i][i];
            lsum += fmaxf(ssim[i][j] - posi + 0.1f, 0.f)
                  + fmaxf(ssim[j][i] - posi + 0.1f, 0.f);
        }
    }
#pragma unroll
    for (int o = 32; o > 0; o >>= 1) {
        lsum += __shfl_down(lsum, o);
        cnt  += __shfl_down(cnt, o);
    }
    int wv = tid >> 6;
    if ((tid & 63) == 0) { rsum[wv] = lsum; rcnt[wv] = cnt; }
    __syncthreads();
    if (tid == 0) {
        float S = 0.f, C = 0.f;
        for (int q = 0; q < 16; ++q) { S += rsum[q]; C += rcnt[q]; }
        out[0] = S / (C + 1e-6f);
    }
}

// ---------------------------------------------------------------------------
extern "C" void kernel_launch(void* const* d_in, const int* in_sizes, int n_in,
                              void* d_out, int out_size, void* d_ws, size_t ws_size,
                              hipStream_t stream) {
    const float* imFtr  = (const float*)d_in[0];  // 64 x 2048 x 1024 fp32
    const float* disFtr = (const float*)d_in[1];  // 64 x 1024 fp32
    const int*   lbl    = (const int*)d_in[2];    // 64 int
    float* out = (float*)d_out;

    __bf16* dis_bf   = (__bf16*)d_ws;                          // 128 KB
    float*  partial  = (float*)((char*)d_ws + NB * ND * 2);    // 256 KB

    cvt_dis_kernel<<<64, 256, 0, stream>>>(disFtr, dis_bf);
    simmax_kernel<<<1024, 256, 0, stream>>>(imFtr, dis_bf, partial);
    loss_kernel<<<1, 1024, 0, stream>>>(partial, lbl, out);
}